// Round 2
// baseline (497.284 us; speedup 1.0000x reference)
//
#include <hip/hip_runtime.h>
#include <math.h>

#define B_TOT 32768
#define NPB 4                 // one wave = one batch element (per iteration), 4 per block

// conv1 tile: transposed [w][h][d] rows; stride 132 floats (126 used), 16B-aligned.
// Layout: rows 0..3 = w0 h0..h3, rows 4..7 = w1 h0..h3, row 8 = shared zero row.
#define RS1 132
#define W1S (4 * RS1)         // 528 : w-stride
#define ZROW (8 * RS1)        // 1056: zero row (stays zero; h-halo + conv2 halo reads)
#define XS_SZ 1216            // 9*132 = 1188, rounded to float4 multiple

// pool1 tile aliased into dead x region after conv1: [w][h][dd], stride 37 (odd)
#define P_RS 37               // rows 0..7 -> floats [0,296)
#define F2_OFF 320            // 80 floats, float4-aligned for vectorized fcm1 reads
#define V11_OFF 400           // 11 floats

typedef float vf4 __attribute__((ext_vector_type(4)));
typedef float vf2 __attribute__((ext_vector_type(2)));

// wave-level sync: buffers are wave-private; avoid s_barrier's vmcnt(0) drain
__device__ __forceinline__ void wave_sync() {
    __builtin_amdgcn_s_waitcnt(0xC07F);    // lgkmcnt(0) only (vm/exp left pending)
    __builtin_amdgcn_wave_barrier();
}

__global__ __launch_bounds__(256, 6) void encoder_kernel(
    const float* __restrict__ x1, const float* __restrict__ x2,
    const float* __restrict__ w1, const float* __restrict__ b1,
    const float* __restrict__ w2, const float* __restrict__ b2,
    const float* __restrict__ fcm1_w, const float* __restrict__ fcm1_b,
    const float* __restrict__ fc_w, const float* __restrict__ fc_b,
    float* __restrict__ out)
{
    __shared__ __align__(16) float xs[NPB][XS_SZ];   // 19456 B/block

    const int tid  = threadIdx.x;
    const int wv   = tid >> 6, lane = tid & 63;
    const int NW   = gridDim.x * NPB;                // total waves = batch stride
    long b = (long)blockIdx.x * NPB + wv;            // first batch of this wave

    // output layout (flat f32, tuple order: z, aug_xm, aug_x_sd, pool1_idx, pool2_idx)
    const size_t XM0 = (size_t)B_TOT * 100;
    const size_t SD0 = XM0 + (size_t)B_TOT * 960;
    const size_t P10 = SD0 + (size_t)B_TOT;
    const size_t P20 = P10 + (size_t)B_TOT * 240;

    // ---- conv weights: uniform loads -> SGPRs, loaded ONCE for all batches ----
    float w1r[21], w2r[21];
    #pragma unroll
    for (int k = 0; k < 21; k++) { w1r[k] = w1[k]; w2r[k] = w2[k]; }
    const float bb1 = b1[0], bb2 = b2[0];

    // ---- prefetch first batch into registers (16 VGPRs) ----
    vf4 pf0 = (vf4){0,0,0,0}, pf1 = pf0, pf2 = pf0, pf3 = pf0;
    {
        const vf4* xin = (const vf4*)(x1 + b * 960);
        pf0 = xin[lane]; pf1 = xin[lane + 64]; pf2 = xin[lane + 128];
        if (lane < 48) pf3 = xin[lane + 192];
    }

    for (;;) {
        const long nb = b + NW;

        // ---- zero tile (halos + zero row; also wipes stale p1/f2/v11 aliases) ----
        {
            const vf4 z4 = (vf4){0.f, 0.f, 0.f, 0.f};
            vf4* xz = (vf4*)xs[wv];
            #pragma unroll
            for (int t = 0; t < 5; t++) { int i = lane + 64 * t; if (i < XS_SZ / 4) xz[i] = z4; }
        }

        // ---- aug_xm passthrough (NT) + transposed scatter from prefetch regs ----
        {
            vf4* xo = (vf4*)(out + XM0 + b * 960);
            __builtin_nontemporal_store(pf0, &xo[lane]);
            __builtin_nontemporal_store(pf1, &xo[lane + 64]);
            __builtin_nontemporal_store(pf2, &xo[lane + 128]);
            if (lane < 48) __builtin_nontemporal_store(pf3, &xo[lane + 192]);

            // float4 at index i covers e=4i..4i+3: d=i>>1, h=2*(i&1)+(c>>1), w=c&1
            auto scat = [&](int i, vf4 v) {
                int bd = (i >> 1) + 3;             // d-halo offset +3
                int hb = 2 * (i & 1);
                xs[wv][ hb      * RS1       + bd] = v.x;   // w=0
                xs[wv][ hb      * RS1 + W1S + bd] = v.y;   // w=1
                xs[wv][(hb + 1) * RS1       + bd] = v.z;
                xs[wv][(hb + 1) * RS1 + W1S + bd] = v.w;
            };
            scat(lane,       pf0);
            scat(lane + 64,  pf1);
            scat(lane + 128, pf2);
            if (lane < 48) scat(lane + 192, pf3);
        }

        // ---- issue next-batch prefetch NOW; lands during this batch's compute ----
        if (nb < B_TOT) {
            const vf4* xin = (const vf4*)(x1 + nb * 960);
            pf0 = xin[lane]; pf1 = xin[lane + 64]; pf2 = xin[lane + 128];
            if (lane < 48) pf3 = xin[lane + 192];
        }
        wave_sync();

        // ---- conv1 (7,3,1) pad(3,1,0) + ReLU + maxpool D/4 (+indices) ----
        // row-streaming: 4 accumulators, one 10-float row live at a time (low VGPR)
        float pv[4];
        #pragma unroll
        for (int t = 0; t < 4; t++) {
            int p = lane + 64 * t;                 // 240 pooled outputs
            float best = 0.f;
            if (p < 240) {
                int dd = p >> 3, h = (p >> 1) & 3, w = p & 1;
                int d0 = 4 * dd;                   // 16B-aligned read base
                float a0 = bb1, a1 = bb1, a2 = bb1, a3 = bb1;
                #pragma unroll
                for (int kh = 0; kh < 3; kh++) {
                    int r = h + kh - 1;
                    int base = ((unsigned)r < 4u) ? (w * W1S + r * RS1 + d0) : (ZROW + d0);
                    const float* bp = &xs[wv][base];
                    vf4 q0 = *(const vf4*)bp;
                    vf4 q1 = *(const vf4*)(bp + 4);
                    vf2 q2 = *(const vf2*)(bp + 8);
                    float row[10] = {q0.x,q0.y,q0.z,q0.w,q1.x,q1.y,q1.z,q1.w,q2.x,q2.y};
                    #pragma unroll
                    for (int kd = 0; kd < 7; kd++) {
                        float wk = w1r[kd * 3 + kh];
                        a0 = fmaf(row[kd],     wk, a0);
                        a1 = fmaf(row[kd + 1], wk, a1);
                        a2 = fmaf(row[kd + 2], wk, a2);
                        a3 = fmaf(row[kd + 3], wk, a3);
                    }
                }
                int bj = 0;
                best = fmaxf(a0, 0.f);
                float v1 = fmaxf(a1, 0.f); if (v1 > best) { best = v1; bj = 1; }
                float v2 = fmaxf(a2, 0.f); if (v2 > best) { best = v2; bj = 2; }
                float v3 = fmaxf(a3, 0.f); if (v3 > best) { best = v3; bj = 3; }
                __builtin_nontemporal_store(
                    (float)(((dd * 4 + bj) * 4 + h) * 2 + w), &out[P10 + b * 240 + p]);
            }
            pv[t] = best;
        }
        wave_sync();

        // ---- write p1 tile into dead x region: halo zeros + pooled values ----
        if (lane < 48) {                           // 8 rows x 6 halo floats
            int row = lane / 6, pos = lane - row * 6;
            xs[wv][row * P_RS + (pos < 3 ? pos : pos + 30)] = 0.f;
        }
        #pragma unroll
        for (int t = 0; t < 4; t++) {
            int p = lane + 64 * t;
            if (p < 240) {
                int dd = p >> 3, h = (p >> 1) & 3, w = p & 1;
                xs[wv][(4 * w + h) * P_RS + dd + 3] = pv[t];
            }
        }
        wave_sync();

        // ---- conv2 + ReLU + maxpool D/3 (+indices) ----
        #pragma unroll
        for (int t = 0; t < 2; t++) {
            int p = lane + 64 * t;                 // 80 pooled outputs
            if (p < 80) {
                int dd = p >> 3, h = (p >> 1) & 3, w = p & 1;
                int d0 = 3 * dd;
                float a0 = bb2, a1 = bb2, a2 = bb2;
                #pragma unroll
                for (int kh = 0; kh < 3; kh++) {
                    int r = h + kh - 1;
                    int base = ((unsigned)r < 4u) ? ((4 * w + r) * P_RS + d0) : (ZROW + d0);
                    float row[9];
                    #pragma unroll
                    for (int c = 0; c < 9; c++) row[c] = xs[wv][base + c];
                    #pragma unroll
                    for (int kd = 0; kd < 7; kd++) {
                        float wk = w2r[kd * 3 + kh];
                        a0 = fmaf(row[kd],     wk, a0);
                        a1 = fmaf(row[kd + 1], wk, a1);
                        a2 = fmaf(row[kd + 2], wk, a2);
                    }
                }
                int bj = 0;
                float best = fmaxf(a0, 0.f);
                float v1 = fmaxf(a1, 0.f); if (v1 > best) { best = v1; bj = 1; }
                float v2 = fmaxf(a2, 0.f); if (v2 > best) { best = v2; bj = 2; }
                xs[wv][F2_OFF + p] = best;         // disjoint from p1 rows: no hazard
                __builtin_nontemporal_store(
                    (float)(((dd * 3 + bj) * 4 + h) * 2 + w), &out[P20 + b * 80 + p]);
            }
        }
        wave_sync();

        // ---- fcm1 (80->10, 4-way split) + ELU; sigmoid(x2). Weights from L1/L2. ----
        if (lane < 40) {
            int o = lane >> 2, q = lane & 3;
            const vf4* fp = (const vf4*)&xs[wv][F2_OFF + q * 20];   // 16B aligned
            const vf4* wp = (const vf4*)(fcm1_w + o * 80 + q * 20); // 16B aligned
            float acc = 0.f;
            #pragma unroll
            for (int k = 0; k < 5; k++) {
                vf4 a = fp[k], c = wp[k];
                acc = fmaf(a.x, c.x, fmaf(a.y, c.y, fmaf(a.z, c.z, fmaf(a.w, c.w, acc))));
            }
            acc += __shfl_xor(acc, 1);
            acc += __shfl_xor(acc, 2);
            if (q == 0) {
                acc += fcm1_b[o];
                xs[wv][V11_OFF + o] = (acc > 0.f) ? acc : expm1f(acc);   // ELU
            }
        } else if (lane == 40) {
            float xv = x2[b];
            xs[wv][V11_OFF + 10] = 1.f / (1.f + expf(-xv));
            __builtin_nontemporal_store(xv, &out[SD0 + b]);
        }
        wave_sync();

        // ---- fc (11->100) + BN-eval scale ----
        {
            float fw0[11], fw1[11], fb0, fb1 = 0.f;
            #pragma unroll
            for (int k = 0; k < 11; k++) { fw0[k] = fc_w[lane * 11 + k]; fw1[k] = 0.f; }
            fb0 = fc_b[lane];
            if (lane < 36) {
                #pragma unroll
                for (int k = 0; k < 11; k++) fw1[k] = fc_w[(64 + lane) * 11 + k];
                fb1 = fc_b[64 + lane];
            }
            const float scale = 0.9999950000374997f;   // 1/sqrt(1+1e-5)
            float vv[11];
            #pragma unroll
            for (int i = 0; i < 11; i++) vv[i] = xs[wv][V11_OFF + i];  // broadcast reads
            float a0 = fb0;
            #pragma unroll
            for (int i = 0; i < 11; i++) a0 = fmaf(vv[i], fw0[i], a0);
            __builtin_nontemporal_store(a0 * scale, &out[b * 100 + lane]);
            if (lane < 36) {
                float a1 = fb1;
                #pragma unroll
                for (int i = 0; i < 11; i++) a1 = fmaf(vv[i], fw1[i], a1);
                __builtin_nontemporal_store(a1 * scale, &out[b * 100 + 64 + lane]);
            }
        }

        b = nb;
        if (b >= B_TOT) break;
        wave_sync();   // v11 reads drained before next iteration's zero overwrites
    }
}

extern "C" void kernel_launch(void* const* d_in, const int* in_sizes, int n_in,
                              void* d_out, int out_size, void* d_ws, size_t ws_size,
                              hipStream_t stream) {
    const float* x1     = (const float*)d_in[0];
    const float* x2     = (const float*)d_in[1];
    const float* w1     = (const float*)d_in[4];
    const float* b1     = (const float*)d_in[5];
    const float* w2     = (const float*)d_in[6];
    const float* b2     = (const float*)d_in[7];
    const float* fcm1_w = (const float*)d_in[8];
    const float* fcm1_b = (const float*)d_in[9];
    const float* fc_w   = (const float*)d_in[10];
    const float* fc_b   = (const float*)d_in[11];
    float* out = (float*)d_out;

    // grid = exactly the resident capacity (persistent waves, no block churn)
    static int s_grid = 0;
    if (s_grid == 0) {
        int nb = 0;
        if (hipOccupancyMaxActiveBlocksPerMultiprocessor(&nb, encoder_kernel, 256, 0)
                != hipSuccess || nb < 1)
            nb = 6;
        long g = (long)nb * 256;                 // 256 CUs on MI355X
        if (g > B_TOT / NPB) g = B_TOT / NPB;
        s_grid = (int)g;
    }

    dim3 grid(s_grid), block(256);
    encoder_kernel<<<grid, block, 0, stream>>>(x1, x2, w1, b1, w2, b2,
                                               fcm1_w, fcm1_b, fc_w, fc_b, out);
}

// Round 3
// 354.137 us; speedup vs baseline: 1.4042x; 1.4042x over previous
//
#include <hip/hip_runtime.h>
#include <math.h>

#define B_TOT 32768
#define NPB 4                 // one wave = one batch element, 4 per block

// conv1 tile: [h][d*2+w] interleaved rows; 4 data rows + shared zero row.
// Row = (120+6 halo)*2 = 252 floats exactly; 252%32=28 -> staggered banks.
#define RS1 252
#define ZR  1008              // zero row (row 4): also conv2's h-halo
#define TILE 1260             // 5*252 floats = 5040 B/wave -> 20160 B/block (8 blk/CU)

// pool1 tile aliased into dead x rows after conv1: [h][dd*2+w], row = (30+6)*2
#define PRS 72                // rows 0..3 -> floats [0,288)
#define F2O 512               // 80 floats, 16B-aligned, in dead zone [288,1008)
#define V11O 600              // 11 floats

typedef float vf4 __attribute__((ext_vector_type(4)));
typedef float vf2 __attribute__((ext_vector_type(2)));

// packed f32 FMA: each half is an IEEE fma -> per-accumulator chain bit-exact
// with the scalar kd-outer/kh-inner version (v_pk_fma_f32 on gfx950)
static __device__ __forceinline__ vf2 fma2(vf2 a, float w, vf2 c) {
    return __builtin_elementwise_fma(a, (vf2){w, w}, c);
}

// wave-level sync: buffers are wave-private; avoid s_barrier's vmcnt(0) drain
__device__ __forceinline__ void wave_sync() {
    __builtin_amdgcn_s_waitcnt(0xC07F);    // lgkmcnt(0) only
    __builtin_amdgcn_wave_barrier();
}

__global__ __launch_bounds__(256, 8) void encoder_kernel(
    const float* __restrict__ x1, const float* __restrict__ x2,
    const float* __restrict__ w1, const float* __restrict__ b1,
    const float* __restrict__ w2, const float* __restrict__ b2,
    const float* __restrict__ fcm1_w, const float* __restrict__ fcm1_b,
    const float* __restrict__ fc_w, const float* __restrict__ fc_b,
    float* __restrict__ out)
{
    __shared__ __align__(16) float xs[NPB][TILE];   // 20160 B/block

    const int tid  = threadIdx.x;
    const int wv   = tid >> 6, lane = tid & 63;
    const long b   = (long)blockIdx.x * NPB + wv;

    // output layout (flat f32: z, aug_xm, aug_x_sd, pool1_idx, pool2_idx)
    const size_t XM0 = (size_t)B_TOT * 100;
    const size_t SD0 = XM0 + (size_t)B_TOT * 960;
    const size_t P10 = SD0 + (size_t)B_TOT;
    const size_t P20 = P10 + (size_t)B_TOT * 240;

    // ---- conv weights: uniform loads -> SGPRs ----
    float w1r[21], w2r[21];
    #pragma unroll
    for (int k = 0; k < 21; k++) { w1r[k] = w1[k]; w2r[k] = w2[k]; }
    const float bb1 = b1[0], bb2 = b2[0];

    // ---- zero tile (halos + zero row + aliased regions) ----
    {
        const vf4 z4 = (vf4){0.f, 0.f, 0.f, 0.f};
        vf4* xz = (vf4*)xs[wv];
        #pragma unroll
        for (int t = 0; t < 5; t++) { int i = lane + 64 * t; if (i < TILE / 4) xz[i] = z4; }
    }
    wave_sync();

    // ---- stage x1 -> LDS (w-interleaved, b64 pairs) + aug_xm copy (plain) ----
    {
        const vf4* xin = (const vf4*)(x1 + b * 960);
        vf4*       xo  = (vf4*)(out + XM0 + b * 960);
        #pragma unroll
        for (int t = 0; t < 4; t++) {
            int i = lane + 64 * t;                 // 240 float4 per batch
            if (i < 240) {
                vf4 v = xin[i];
                xo[i] = v;
                // e=4i+c: d=i>>1, h=2(i&1)+(c>>1), w=c&1 -> (v.x,v.y)=h0 pair, (v.z,v.w)=h1 pair
                int d  = i >> 1;
                int h0 = 2 * (i & 1);
                int fo = 2 * (d + 3);              // d-halo offset +3 (in float2 units)
                *(vf2*)&xs[wv][ h0      * RS1 + fo] = (vf2){v.x, v.y};
                *(vf2*)&xs[wv][(h0 + 1) * RS1 + fo] = (vf2){v.z, v.w};
            }
        }
    }
    wave_sync();

    // ---- conv1 (7,3,1) pad(3,1,0) + ReLU + maxpool D/4 (+indices), w-packed ----
    // item = dd*4+h handles BOTH w via float2; sliding 4-slot window per row
    auto conv1_item = [&](int item) -> vf2 {
        const int dd = item >> 2, h = item & 3;
        const float* T = xs[wv];
        int rb[3];
        #pragma unroll
        for (int kh = 0; kh < 3; kh++) {
            int r = h + kh - 1;
            rb[kh] = (((unsigned)r < 4u) ? r * RS1 : ZR) + 8 * dd;
        }
        vf2 A[3][4];
        #pragma unroll
        for (int kh = 0; kh < 3; kh++)
            #pragma unroll
            for (int p = 0; p < 4; p++)
                A[kh][p] = *(const vf2*)&T[rb[kh] + 2 * p];
        vf2 a0 = (vf2){bb1, bb1}, a1 = a0, a2 = a0, a3 = a0;
        #pragma unroll
        for (int kd = 0; kd < 7; kd++) {
            const float wA = w1r[3 * kd], wB = w1r[3 * kd + 1], wC = w1r[3 * kd + 2];
            a0 = fma2(A[0][ kd      & 3], wA, a0);
            a0 = fma2(A[1][ kd      & 3], wB, a0);
            a0 = fma2(A[2][ kd      & 3], wC, a0);
            a1 = fma2(A[0][(kd + 1) & 3], wA, a1);
            a1 = fma2(A[1][(kd + 1) & 3], wB, a1);
            a1 = fma2(A[2][(kd + 1) & 3], wC, a1);
            a2 = fma2(A[0][(kd + 2) & 3], wA, a2);
            a2 = fma2(A[1][(kd + 2) & 3], wB, a2);
            a2 = fma2(A[2][(kd + 2) & 3], wC, a2);
            a3 = fma2(A[0][(kd + 3) & 3], wA, a3);
            a3 = fma2(A[1][(kd + 3) & 3], wB, a3);
            a3 = fma2(A[2][(kd + 3) & 3], wC, a3);
            if (kd < 6) {
                #pragma unroll
                for (int kh = 0; kh < 3; kh++)
                    A[kh][kd & 3] = *(const vf2*)&T[rb[kh] + 2 * (kd + 4)];
            }
        }
        // ReLU + pool over j (first-max tiebreak, matches jnp.argmax)
        float bv0 = fmaxf(a0.x, 0.f); int j0 = 0;
        float q;
        q = fmaxf(a1.x, 0.f); if (q > bv0) { bv0 = q; j0 = 1; }
        q = fmaxf(a2.x, 0.f); if (q > bv0) { bv0 = q; j0 = 2; }
        q = fmaxf(a3.x, 0.f); if (q > bv0) { bv0 = q; j0 = 3; }
        float bv1 = fmaxf(a0.y, 0.f); int j1 = 0;
        q = fmaxf(a1.y, 0.f); if (q > bv1) { bv1 = q; j1 = 1; }
        q = fmaxf(a2.y, 0.f); if (q > bv1) { bv1 = q; j1 = 2; }
        q = fmaxf(a3.y, 0.f); if (q > bv1) { bv1 = q; j1 = 3; }
        vf2 ix = {(float)(((dd * 4 + j0) * 4 + h) * 2),
                  (float)(((dd * 4 + j1) * 4 + h) * 2 + 1)};
        *(vf2*)&out[P10 + b * 240 + (size_t)item * 2] = ix;
        return (vf2){bv0, bv1};
    };
    vf2 bp0 = conv1_item(lane);                    // items 0..63
    vf2 bp1 = (vf2){0.f, 0.f};
    if (lane < 56) bp1 = conv1_item(64 + lane);    // items 64..119
    wave_sync();

    // ---- p1 tile into dead x rows: halo zeros + pooled float2 values ----
    if (lane < 48) {                               // 4 rows x 12 halo floats
        int row = lane / 12, pos = lane - row * 12;
        xs[wv][row * PRS + (pos < 6 ? pos : pos + 60)] = 0.f;
    }
    {
        int it0 = lane;
        *(vf2*)&xs[wv][(it0 & 3) * PRS + 2 * ((it0 >> 2) + 3)] = bp0;
        if (lane < 56) {
            int it1 = 64 + lane;
            *(vf2*)&xs[wv][(it1 & 3) * PRS + 2 * ((it1 >> 2) + 3)] = bp1;
        }
    }
    wave_sync();

    // ---- conv2 + ReLU + maxpool D/3 (+indices), w-packed ----
    if (lane < 40) {                               // item = dd*4+h, dd 0..9
        const int item = lane, dd = item >> 2, h = item & 3;
        const float* T = xs[wv];
        int rb[3];
        #pragma unroll
        for (int kh = 0; kh < 3; kh++) {
            int r = h + kh - 1;
            rb[kh] = (((unsigned)r < 4u) ? r * PRS : ZR) + 6 * dd;
        }
        vf2 A[3][3];
        #pragma unroll
        for (int kh = 0; kh < 3; kh++)
            #pragma unroll
            for (int p = 0; p < 3; p++)
                A[kh][p] = *(const vf2*)&T[rb[kh] + 2 * p];
        vf2 a0 = (vf2){bb2, bb2}, a1 = a0, a2 = a0;
        #pragma unroll
        for (int kd = 0; kd < 7; kd++) {
            const float wA = w2r[3 * kd], wB = w2r[3 * kd + 1], wC = w2r[3 * kd + 2];
            int s0 = kd % 3, s1 = (kd + 1) % 3, s2 = (kd + 2) % 3;
            a0 = fma2(A[0][s0], wA, a0);
            a0 = fma2(A[1][s0], wB, a0);
            a0 = fma2(A[2][s0], wC, a0);
            a1 = fma2(A[0][s1], wA, a1);
            a1 = fma2(A[1][s1], wB, a1);
            a1 = fma2(A[2][s1], wC, a1);
            a2 = fma2(A[0][s2], wA, a2);
            a2 = fma2(A[1][s2], wB, a2);
            a2 = fma2(A[2][s2], wC, a2);
            if (kd < 6) {
                #pragma unroll
                for (int kh = 0; kh < 3; kh++)
                    A[kh][kd % 3] = *(const vf2*)&T[rb[kh] + 2 * (kd + 3)];
            }
        }
        float bv0 = fmaxf(a0.x, 0.f); int j0 = 0;
        float q;
        q = fmaxf(a1.x, 0.f); if (q > bv0) { bv0 = q; j0 = 1; }
        q = fmaxf(a2.x, 0.f); if (q > bv0) { bv0 = q; j0 = 2; }
        float bv1 = fmaxf(a0.y, 0.f); int j1 = 0;
        q = fmaxf(a1.y, 0.f); if (q > bv1) { bv1 = q; j1 = 1; }
        q = fmaxf(a2.y, 0.f); if (q > bv1) { bv1 = q; j1 = 2; }
        *(vf2*)&xs[wv][F2O + item * 2] = (vf2){bv0, bv1};   // xm flatten order
        vf2 ix = {(float)(((dd * 3 + j0) * 4 + h) * 2),
                  (float)(((dd * 3 + j1) * 4 + h) * 2 + 1)};
        *(vf2*)&out[P20 + b * 80 + (size_t)item * 2] = ix;
    }
    wave_sync();

    // ---- fcm1 (80->10, 4-way split) + ELU; sigmoid(x2) ----
    if (lane < 40) {
        int o = lane >> 2, q4 = lane & 3;
        const vf4* fp = (const vf4*)&xs[wv][F2O + q4 * 20];   // 16B aligned
        const vf4* wp = (const vf4*)(fcm1_w + o * 80 + q4 * 20);
        float acc = 0.f;
        #pragma unroll
        for (int k = 0; k < 5; k++) {
            vf4 a = fp[k], c = wp[k];
            acc = fmaf(a.x, c.x, fmaf(a.y, c.y, fmaf(a.z, c.z, fmaf(a.w, c.w, acc))));
        }
        acc += __shfl_xor(acc, 1);
        acc += __shfl_xor(acc, 2);
        if (q4 == 0) {
            acc += fcm1_b[o];
            xs[wv][V11O + o] = (acc > 0.f) ? acc : expm1f(acc);   // ELU
        }
    } else if (lane == 40) {
        float xv = x2[b];
        xs[wv][V11O + 10] = 1.f / (1.f + expf(-xv));
        out[SD0 + b] = xv;
    }
    wave_sync();

    // ---- fc (11->100) + BN-eval scale ----
    {
        float fw0[11], fw1[11], fb0, fb1 = 0.f;
        #pragma unroll
        for (int k = 0; k < 11; k++) { fw0[k] = fc_w[lane * 11 + k]; fw1[k] = 0.f; }
        fb0 = fc_b[lane];
        if (lane < 36) {
            #pragma unroll
            for (int k = 0; k < 11; k++) fw1[k] = fc_w[(64 + lane) * 11 + k];
            fb1 = fc_b[64 + lane];
        }
        const float scale = 0.9999950000374997f;   // 1/sqrt(1+1e-5)
        float vv[11];
        #pragma unroll
        for (int i = 0; i < 11; i++) vv[i] = xs[wv][V11O + i];  // broadcast reads
        float a0 = fb0;
        #pragma unroll
        for (int i = 0; i < 11; i++) a0 = fmaf(vv[i], fw0[i], a0);
        out[b * 100 + lane] = a0 * scale;
        if (lane < 36) {
            float a1 = fb1;
            #pragma unroll
            for (int i = 0; i < 11; i++) a1 = fmaf(vv[i], fw1[i], a1);
            out[b * 100 + 64 + lane] = a1 * scale;
        }
    }
}

extern "C" void kernel_launch(void* const* d_in, const int* in_sizes, int n_in,
                              void* d_out, int out_size, void* d_ws, size_t ws_size,
                              hipStream_t stream) {
    const float* x1     = (const float*)d_in[0];
    const float* x2     = (const float*)d_in[1];
    const float* w1     = (const float*)d_in[4];
    const float* b1     = (const float*)d_in[5];
    const float* w2     = (const float*)d_in[6];
    const float* b2     = (const float*)d_in[7];
    const float* fcm1_w = (const float*)d_in[8];
    const float* fcm1_b = (const float*)d_in[9];
    const float* fc_w   = (const float*)d_in[10];
    const float* fc_b   = (const float*)d_in[11];
    float* out = (float*)d_out;

    dim3 grid(B_TOT / NPB), block(256);
    encoder_kernel<<<grid, block, 0, stream>>>(x1, x2, w1, b1, w2, b2,
                                               fcm1_w, fcm1_b, fc_w, fc_b, out);
}